// Round 3
// baseline (264.979 us; speedup 1.0000x reference)
//
#include <hip/hip_runtime.h>
#include <math.h>

// CircleLoss fused, MFMA + symmetry version.
// sim = xn @ xn^T, split-bf16: sim ~= hi.hi + hi.lo + lo.hi (drop lo.lo ~2^-18).
// sim and the positive mask are symmetric -> compute upper-triangular 128x128
// block pairs only; off-diagonal blocks contribute row sums to g[i] AND
// column sums to g[j]. loss = mean(log1p(sumP*sumN)) (softplus(lp+ln)).
// (-logit_p in [-252,4], logit_n in [0,36] -> f32 exp-sums safe.)
//
// LDS XOR swizzle: chunk c (16B) of row r lives at slot c ^ ((r>>1)&3); staging
// permutes each lane's GLOBAL source (global_load_lds LDS dest is lane-pinned),
// frag reads apply the same XOR -> every 8-lane octet of ds_read_b128 covers
// all 32 banks (conflict-free).

#define NR   8192
#define DIMK 128
#define NT   64                    // 8192/128 row-tiles
#define NBLK (NT * (NT + 1) / 2)   // 2080 upper-tri block pairs

typedef __attribute__((ext_vector_type(8))) short short8;   // 8 bf16
typedef __attribute__((ext_vector_type(4))) float f32x4;
typedef __attribute__((address_space(3))) uint32_t lds_u32;
typedef const __attribute__((address_space(1))) uint32_t glb_u32;

__device__ __forceinline__ unsigned short bf16_rne(float f) {
  uint32_t u = __float_as_uint(f);
  u += 0x7FFFu + ((u >> 16) & 1u);
  return (unsigned short)(u >> 16);
}

// ws: xhi bf16[NR*DIMK] (2MB) | xlo (2MB) | gP f32[NR] | gN f32[NR] | counter

__global__ __launch_bounds__(256) void normalize_split_kernel(
    const float* __restrict__ x, unsigned short* __restrict__ xhi,
    unsigned short* __restrict__ xlo, float* __restrict__ gP,
    float* __restrict__ gN, int* __restrict__ counter) {
  // fused zero-init of accumulators + completion counter
  if (blockIdx.x < 32)      gP[blockIdx.x * 256 + threadIdx.x] = 0.f;
  else if (blockIdx.x < 64) gN[(blockIdx.x - 32) * 256 + threadIdx.x] = 0.f;
  if (blockIdx.x == 64 && threadIdx.x == 0) *counter = 0;

  const int wave = threadIdx.x >> 6;
  const int lane = threadIdx.x & 63;
  const int row  = blockIdx.x * 4 + wave;
  const float2 v = ((const float2*)(x + (size_t)row * DIMK))[lane];
  float ss = v.x * v.x + v.y * v.y;
  #pragma unroll
  for (int s = 1; s < 64; s <<= 1) ss += __shfl_xor(ss, s);
  const float r = rsqrtf(ss);
  const float a = v.x * r, b = v.y * r;
  const unsigned short ha = bf16_rne(a), hb = bf16_rne(b);
  const float haf = __uint_as_float((uint32_t)ha << 16);
  const float hbf = __uint_as_float((uint32_t)hb << 16);
  ushort2 hi, lo;
  hi.x = ha; hi.y = hb;
  lo.x = bf16_rne(a - haf); lo.y = bf16_rne(b - hbf);
  ((ushort2*)xhi)[(size_t)row * 64 + lane] = hi;
  ((ushort2*)xlo)[(size_t)row * 64 + lane] = lo;
}

__global__ __launch_bounds__(256) void simloss_kernel(
    const unsigned short* __restrict__ xhi, const unsigned short* __restrict__ xlo,
    const int* __restrict__ tgt, float* __restrict__ gP, float* __restrict__ gN,
    int* __restrict__ counter, float* __restrict__ out) {
  __shared__ unsigned short AsH[128 * 32], AsL[128 * 32];
  __shared__ unsigned short BsH[128 * 32], BsL[128 * 32];
  __shared__ int tAs[128], tBs[128];
  __shared__ float red[256];
  __shared__ int islast;

  // ---- triangular decode: idx -> (bi, bj), bi <= bj ----
  const int idx = blockIdx.x;
  int bi = (int)floorf((129.0f - sqrtf(129.0f * 129.0f - 8.0f * (float)idx)) * 0.5f);
  if (bi < 0) bi = 0;
  if (bi > NT - 1) bi = NT - 1;
  while (NT * bi - bi * (bi - 1) / 2 > idx) --bi;
  while (NT * (bi + 1) - (bi + 1) * bi / 2 <= idx) ++bi;
  const int bj = bi + idx - (NT * bi - bi * (bi - 1) / 2);
  const int i0 = bi * 128, j0 = bj * 128;
  const bool offdiag = (bi != bj);

  const int tid  = threadIdx.x;
  const int wave = tid >> 6, lane = tid & 63;
  const int wy = wave >> 1, wx = wave & 1;
  const int q = lane >> 4, mcol = lane & 15;
  const int sw = (mcol >> 1) & 3;          // row-derived XOR for frag reads
  const int ko = (q ^ sw) * 8;             // swizzled ushort k-offset in 32-wide row

  if (tid < 128) tAs[tid] = tgt[i0 + tid];
  else           tBs[tid - 128] = tgt[j0 + tid - 128];

  // staging: wave -> one tile; lane covers 16B; seg = 16 rows x 64B = 1KB
  const unsigned short* gsrc =
      (wave == 0) ? xhi + (size_t)i0 * DIMK :
      (wave == 1) ? xlo + (size_t)i0 * DIMK :
      (wave == 2) ? xhi + (size_t)j0 * DIMK :
                    xlo + (size_t)j0 * DIMK;
  unsigned short* ldst = (wave == 0) ? AsH : (wave == 1) ? AsL
                       : (wave == 2) ? BsH : BsL;
  const int srow   = lane >> 2;
  const int schunk = ((lane & 3) ^ ((lane >> 3) & 3)) * 8;  // swizzled global chunk

  f32x4 acc[4][4];
  #pragma unroll
  for (int r = 0; r < 4; ++r)
    #pragma unroll
    for (int c = 0; c < 4; ++c)
      acc[r][c] = (f32x4){0.f, 0.f, 0.f, 0.f};

  for (int kc = 0; kc < 4; ++kc) {
    __syncthreads();  // previous readers done before overwrite (covers tAs/tBs on kc==0)
    #pragma unroll
    for (int s = 0; s < 8; ++s) {
      const unsigned short* gp =
          gsrc + (size_t)(s * 16 + srow) * DIMK + kc * 32 + schunk;
      __builtin_amdgcn_global_load_lds((glb_u32*)gp, (lds_u32*)&ldst[s * 512], 16, 0, 0);
    }
    __syncthreads();

    short8 ah[4], bh[4], bl[4], al[4];
    #pragma unroll
    for (int r = 0; r < 4; ++r)
      ah[r] = *(const short8*)&AsH[(wy * 64 + r * 16 + mcol) * 32 + ko];
    #pragma unroll
    for (int c = 0; c < 4; ++c)
      bh[c] = *(const short8*)&BsH[(wx * 64 + c * 16 + mcol) * 32 + ko];
    #pragma unroll
    for (int r = 0; r < 4; ++r)
      #pragma unroll
      for (int c = 0; c < 4; ++c)
        acc[r][c] = __builtin_amdgcn_mfma_f32_16x16x32_bf16(ah[r], bh[c], acc[r][c], 0, 0, 0);
    #pragma unroll
    for (int c = 0; c < 4; ++c)
      bl[c] = *(const short8*)&BsL[(wx * 64 + c * 16 + mcol) * 32 + ko];
    #pragma unroll
    for (int r = 0; r < 4; ++r)
      #pragma unroll
      for (int c = 0; c < 4; ++c)
        acc[r][c] = __builtin_amdgcn_mfma_f32_16x16x32_bf16(ah[r], bl[c], acc[r][c], 0, 0, 0);
    #pragma unroll
    for (int r = 0; r < 4; ++r)
      al[r] = *(const short8*)&AsL[(wy * 64 + r * 16 + mcol) * 32 + ko];
    #pragma unroll
    for (int r = 0; r < 4; ++r)
      #pragma unroll
      for (int c = 0; c < 4; ++c)
        acc[r][c] = __builtin_amdgcn_mfma_f32_16x16x32_bf16(al[r], bh[c], acc[r][c], 0, 0, 0);
  }

  // ---- fused epilogue. C layout: col = lane&15, row = q*4 + reg ----
  int tb[4];
  #pragma unroll
  for (int c = 0; c < 4; ++c) tb[c] = tBs[wx * 64 + c * 16 + mcol];

  float colp[4] = {0.f, 0.f, 0.f, 0.f};
  float coln[4] = {0.f, 0.f, 0.f, 0.f};

  #pragma unroll
  for (int r = 0; r < 4; ++r) {
    #pragma unroll
    for (int reg = 0; reg < 4; ++reg) {
      const int ta = tAs[wy * 64 + r * 16 + q * 4 + reg];
      float vsp = 0.f, vsn = 0.f;
      #pragma unroll
      for (int c = 0; c < 4; ++c) {
        const float s  = acc[r][c][reg];
        const bool pos = (ta == tb[c]);
        const float ap = fmaxf(1.25f - s, 0.f);
        const float an = fmaxf(s - 0.25f, 0.f);
        const float arg = pos ? ap * fmaf(s, 64.f, -48.f) : an * an * 64.f;
        const float e = __expf(arg);
        const float ep = pos ? e : 0.f;
        const float en = pos ? 0.f : e;
        vsp += ep; vsn += en;
        colp[c] += ep; coln[c] += en;
      }
      #pragma unroll
      for (int s2 = 1; s2 < 16; s2 <<= 1) {
        vsp += __shfl_xor(vsp, s2);
        vsn += __shfl_xor(vsn, s2);
      }
      if (mcol == 0) {
        const int row = i0 + wy * 64 + r * 16 + q * 4 + reg;
        atomicAdd(&gP[row], vsp);
        atomicAdd(&gN[row], vsn);
      }
    }
  }
  if (offdiag) {  // column sums -> rows j (transpose contributions)
    #pragma unroll
    for (int c = 0; c < 4; ++c) {
      colp[c] += __shfl_xor(colp[c], 16); colp[c] += __shfl_xor(colp[c], 32);
      coln[c] += __shfl_xor(coln[c], 16); coln[c] += __shfl_xor(coln[c], 32);
    }
    if (q == 0) {
      #pragma unroll
      for (int c = 0; c < 4; ++c) {
        const int col = j0 + wx * 64 + c * 16 + mcol;
        atomicAdd(&gP[col], colp[c]);
        atomicAdd(&gN[col], coln[c]);
      }
    }
  }

  // ---- last-block finalize ----
  __threadfence();
  __syncthreads();
  if (tid == 0) islast = (atomicAdd(counter, 1) == NBLK - 1) ? 1 : 0;
  __syncthreads();
  if (islast) {
    __threadfence();
    float local = 0.f;
    for (int i = tid; i < NR; i += 256) {
      const float p = __hip_atomic_load(&gP[i], __ATOMIC_RELAXED, __HIP_MEMORY_SCOPE_AGENT);
      const float n = __hip_atomic_load(&gN[i], __ATOMIC_RELAXED, __HIP_MEMORY_SCOPE_AGENT);
      local += log1pf(p * n);
    }
    red[tid] = local;
    __syncthreads();
    for (int s2 = 128; s2 > 0; s2 >>= 1) {
      if (tid < s2) red[tid] += red[tid + s2];
      __syncthreads();
    }
    if (tid == 0) out[0] = red[0] / (float)NR;
  }
}

extern "C" void kernel_launch(void* const* d_in, const int* in_sizes, int n_in,
                              void* d_out, int out_size, void* d_ws, size_t ws_size,
                              hipStream_t stream) {
  const float* x  = (const float*)d_in[0];
  const int* tgt  = (const int*)d_in[1];
  float* out      = (float*)d_out;

  unsigned short* xhi = (unsigned short*)d_ws;
  unsigned short* xlo = xhi + (size_t)NR * DIMK;
  float* gP = (float*)((char*)d_ws + (size_t)NR * DIMK * 4);
  float* gN = gP + NR;
  int* counter = (int*)(gN + NR);

  normalize_split_kernel<<<NR / 4, 256, 0, stream>>>(x, xhi, xlo, gP, gN, counter);
  simloss_kernel<<<NBLK, 256, 0, stream>>>(xhi, xlo, tgt, gP, gN, counter, out);
}

// Round 4
// 158.318 us; speedup vs baseline: 1.6737x; 1.6737x over previous
//
#include <hip/hip_runtime.h>
#include <math.h>

// CircleLoss fused, MFMA + symmetry, fence-free completion protocol.
// sim = xn @ xn^T, 2-term split-bf16: sim ~= hiA.hiB + loA.hiB = A.hiB
//   (error = A.loB ~ 2e-4 typical; diagonal is stationary for logit_p).
// Upper-triangular 128x128 block pairs; off-diagonal blocks contribute row
// sums to g[i] AND column sums to g[j]. loss = mean(log1p(sumP*sumN)).
// Cross-block protocol: device-scope atomics only (coherent-point), ordered
// by raw s_waitcnt vmcnt(0) -- NO __threadfence (= buffer_wbl2 L2 writeback
// on multi-XCD gfx950, the R3 poison: 2080 blocks x L2 drain).
// Last block reads accumulators via atomicAdd(p, 0.0f) readback.

#define NR   8192
#define DIMK 128
#define NT   64
#define NBLK (NT * (NT + 1) / 2)   // 2080

typedef __attribute__((ext_vector_type(8))) short short8;
typedef __attribute__((ext_vector_type(4))) float f32x4;
typedef __attribute__((address_space(3))) uint32_t lds_u32;
typedef const __attribute__((address_space(1))) uint32_t glb_u32;

__device__ __forceinline__ unsigned short bf16_rne(float f) {
  uint32_t u = __float_as_uint(f);
  u += 0x7FFFu + ((u >> 16) & 1u);
  return (unsigned short)(u >> 16);
}

// ws: xhi bf16[NR*DIMK] (2MB) | xlo (2MB) | gP f32[NR] | gN f32[NR] | counter

__global__ __launch_bounds__(256) void normalize_split_kernel(
    const float* __restrict__ x, unsigned short* __restrict__ xhi,
    unsigned short* __restrict__ xlo, float* __restrict__ gP,
    float* __restrict__ gN, int* __restrict__ counter) {
  if (blockIdx.x < 32)      gP[blockIdx.x * 256 + threadIdx.x] = 0.f;
  else if (blockIdx.x < 64) gN[(blockIdx.x - 32) * 256 + threadIdx.x] = 0.f;
  if (blockIdx.x == 64 && threadIdx.x == 0) *counter = 0;

  const int wave = threadIdx.x >> 6;
  const int lane = threadIdx.x & 63;
  const int row  = blockIdx.x * 4 + wave;
  const float2 v = ((const float2*)(x + (size_t)row * DIMK))[lane];
  float ss = v.x * v.x + v.y * v.y;
  #pragma unroll
  for (int s = 1; s < 64; s <<= 1) ss += __shfl_xor(ss, s);
  const float r = rsqrtf(ss);
  const float a = v.x * r, b = v.y * r;
  const unsigned short ha = bf16_rne(a), hb = bf16_rne(b);
  const float haf = __uint_as_float((uint32_t)ha << 16);
  const float hbf = __uint_as_float((uint32_t)hb << 16);
  ushort2 hi, lo;
  hi.x = ha; hi.y = hb;
  lo.x = bf16_rne(a - haf); lo.y = bf16_rne(b - hbf);
  ((ushort2*)xhi)[(size_t)row * 64 + lane] = hi;
  ((ushort2*)xlo)[(size_t)row * 64 + lane] = lo;
}

__global__ __launch_bounds__(256) void simloss_kernel(
    const unsigned short* __restrict__ xhi, const unsigned short* __restrict__ xlo,
    const int* __restrict__ tgt, float* __restrict__ gP, float* __restrict__ gN,
    int* __restrict__ counter, float* __restrict__ out) {
  __shared__ unsigned short AsH[128 * 32], AsL[128 * 32], BsH[128 * 32];
  __shared__ int tAs[128], tBs[128];
  __shared__ float red[256];
  __shared__ int islast;

  // triangular decode: idx -> (bi, bj), bi <= bj
  const int idx = blockIdx.x;
  int bi = (int)floorf((129.0f - sqrtf(129.0f * 129.0f - 8.0f * (float)idx)) * 0.5f);
  if (bi < 0) bi = 0;
  if (bi > NT - 1) bi = NT - 1;
  while (NT * bi - bi * (bi - 1) / 2 > idx) --bi;
  while (NT * (bi + 1) - (bi + 1) * bi / 2 <= idx) ++bi;
  const int bj = bi + idx - (NT * bi - bi * (bi - 1) / 2);
  const int i0 = bi * 128, j0 = bj * 128;
  const bool offdiag = (bi != bj);

  const int tid  = threadIdx.x;
  const int wave = tid >> 6, lane = tid & 63;
  const int wy = wave >> 1, wx = wave & 1;
  const int q = lane >> 4, mcol = lane & 15;
  const int ko = (q ^ ((mcol >> 1) & 3)) * 8;   // XOR-swizzled k-offset (conflict-free, r3-verified)

  if (tid < 128) tAs[tid] = tgt[i0 + tid];
  else           tBs[tid - 128] = tgt[j0 + tid - 128];

  // staging: 3 tiles x 8 segs = 24 segs, 6 per wave; lane covers 16B
  const unsigned short* ghA = xhi + (size_t)i0 * DIMK;
  const unsigned short* glA = xlo + (size_t)i0 * DIMK;
  const unsigned short* ghB = xhi + (size_t)j0 * DIMK;
  const int srow   = lane >> 2;
  const int schunk = ((lane & 3) ^ ((lane >> 3) & 3)) * 8;  // swizzled global chunk

  f32x4 acc[4][4];
  #pragma unroll
  for (int r = 0; r < 4; ++r)
    #pragma unroll
    for (int c = 0; c < 4; ++c)
      acc[r][c] = (f32x4){0.f, 0.f, 0.f, 0.f};

  for (int kc = 0; kc < 4; ++kc) {
    __syncthreads();  // previous readers done before overwrite (covers tAs/tBs on kc==0)
    #pragma unroll
    for (int t = 0; t < 6; ++t) {
      const int segid = wave * 6 + t;
      const int tile = segid >> 3, seg = segid & 7;
      const unsigned short* g = (tile == 0) ? ghA : (tile == 1) ? glA : ghB;
      unsigned short* l = (tile == 0) ? AsH : (tile == 1) ? AsL : BsH;
      const unsigned short* gp = g + (size_t)(seg * 16 + srow) * DIMK + kc * 32 + schunk;
      __builtin_amdgcn_global_load_lds((glb_u32*)gp, (lds_u32*)&l[seg * 512], 16, 0, 0);
    }
    __syncthreads();

    short8 ah[4], al[4], bh[4];
    #pragma unroll
    for (int r = 0; r < 4; ++r)
      ah[r] = *(const short8*)&AsH[(wy * 64 + r * 16 + mcol) * 32 + ko];
    #pragma unroll
    for (int c = 0; c < 4; ++c)
      bh[c] = *(const short8*)&BsH[(wx * 64 + c * 16 + mcol) * 32 + ko];
    #pragma unroll
    for (int r = 0; r < 4; ++r)
      #pragma unroll
      for (int c = 0; c < 4; ++c)
        acc[r][c] = __builtin_amdgcn_mfma_f32_16x16x32_bf16(ah[r], bh[c], acc[r][c], 0, 0, 0);
    #pragma unroll
    for (int r = 0; r < 4; ++r)
      al[r] = *(const short8*)&AsL[(wy * 64 + r * 16 + mcol) * 32 + ko];
    #pragma unroll
    for (int r = 0; r < 4; ++r)
      #pragma unroll
      for (int c = 0; c < 4; ++c)
        acc[r][c] = __builtin_amdgcn_mfma_f32_16x16x32_bf16(al[r], bh[c], acc[r][c], 0, 0, 0);
  }

  // fused epilogue. C layout: col = lane&15, row = q*4 + reg
  int tb[4];
  #pragma unroll
  for (int c = 0; c < 4; ++c) tb[c] = tBs[wx * 64 + c * 16 + mcol];

  float colp[4] = {0.f, 0.f, 0.f, 0.f};
  float coln[4] = {0.f, 0.f, 0.f, 0.f};

  #pragma unroll
  for (int r = 0; r < 4; ++r) {
    #pragma unroll
    for (int reg = 0; reg < 4; ++reg) {
      const int ta = tAs[wy * 64 + r * 16 + q * 4 + reg];
      float vsp = 0.f, vsn = 0.f;
      #pragma unroll
      for (int c = 0; c < 4; ++c) {
        const float s  = acc[r][c][reg];
        const bool pos = (ta == tb[c]);
        const float ap = fmaxf(1.25f - s, 0.f);
        const float an = fmaxf(s - 0.25f, 0.f);
        const float arg = pos ? ap * fmaf(s, 64.f, -48.f) : an * an * 64.f;
        const float e = __expf(arg);
        const float ep = pos ? e : 0.f;
        const float en = pos ? 0.f : e;
        vsp += ep; vsn += en;
        colp[c] += ep; coln[c] += en;
      }
      #pragma unroll
      for (int s2 = 1; s2 < 16; s2 <<= 1) {
        vsp += __shfl_xor(vsp, s2);
        vsn += __shfl_xor(vsn, s2);
      }
      if (mcol == 0) {
        const int row = i0 + wy * 64 + r * 16 + q * 4 + reg;
        atomicAdd(&gP[row], vsp);
        atomicAdd(&gN[row], vsn);
      }
    }
  }
  if (offdiag) {  // transpose contributions -> rows j
    #pragma unroll
    for (int c = 0; c < 4; ++c) {
      colp[c] += __shfl_xor(colp[c], 16); colp[c] += __shfl_xor(colp[c], 32);
      coln[c] += __shfl_xor(coln[c], 16); coln[c] += __shfl_xor(coln[c], 32);
    }
    if (q == 0) {
      #pragma unroll
      for (int c = 0; c < 4; ++c) {
        const int col = j0 + wx * 64 + c * 16 + mcol;
        atomicAdd(&gP[col], colp[c]);
        atomicAdd(&gN[col], coln[c]);
      }
    }
  }

  // ---- fence-free last-block finalize ----
  // Order: my device-scope atomics ack'd (vmcnt=0) BEFORE counter bump.
  __builtin_amdgcn_s_waitcnt(0);
  __syncthreads();
  if (tid == 0) islast = (atomicAdd(counter, 1) == NBLK - 1) ? 1 : 0;
  __syncthreads();
  if (islast) {
    float local = 0.f;
    for (int i = tid; i < NR; i += 256) {
      // atomic readback at the coherent point (no cache staleness possible)
      const float p = atomicAdd(&gP[i], 0.0f);
      const float n = atomicAdd(&gN[i], 0.0f);
      local += log1pf(p * n);
    }
    red[tid] = local;
    __syncthreads();
    for (int s2 = 128; s2 > 0; s2 >>= 1) {
      if (tid < s2) red[tid] += red[tid + s2];
      __syncthreads();
    }
    if (tid == 0) out[0] = red[0] / (float)NR;
  }
}

extern "C" void kernel_launch(void* const* d_in, const int* in_sizes, int n_in,
                              void* d_out, int out_size, void* d_ws, size_t ws_size,
                              hipStream_t stream) {
  const float* x  = (const float*)d_in[0];
  const int* tgt  = (const int*)d_in[1];
  float* out      = (float*)d_out;

  unsigned short* xhi = (unsigned short*)d_ws;
  unsigned short* xlo = xhi + (size_t)NR * DIMK;
  float* gP = (float*)((char*)d_ws + (size_t)NR * DIMK * 4);
  float* gN = gP + NR;
  int* counter = (int*)(gN + NR);

  normalize_split_kernel<<<NR / 4, 256, 0, stream>>>(x, xhi, xlo, gP, gN, counter);
  simloss_kernel<<<NBLK, 256, 0, stream>>>(xhi, xlo, tgt, gP, gN, counter, out);
}

// Round 5
// 151.446 us; speedup vs baseline: 1.7497x; 1.0454x over previous
//
#include <hip/hip_runtime.h>
#include <math.h>

// CircleLoss fused, MFMA + symmetry, fence-free completion protocol.
// sim = xn @ xn^T, 2-term split-bf16: sim ~= hiA.hiB + loA.hiB = A.hiB
//   (error = A.loB ~ 2e-4 typical; diagonal is stationary for logit_p).
// Upper-triangular 128x128 block pairs; off-diagonal blocks contribute row
// sums to g[i] AND column sums to g[j]. loss = mean(log1p(sumP*sumN)).
// Cross-block protocol: device-scope atomics only, ordered by raw
// s_waitcnt(0) -- NO __threadfence (= buffer_wbl2 L2 writeback on gfx950,
// the R3 poison). Last block reads accumulators via BATCHED atomicAdd(p,0)
// readbacks (16 independent in flight -- R4's dependent loop was a ~25us
// serial tail).
// R5: BK=64 staging (2 barrier-drains per block instead of 4; 48KB LDS,
// 3 blocks/CU). 128B LDS rows, XOR swizzle slot = chunk ^ (row&7) ->
// 2-way bank aliasing (free, m136).

#define NR   8192
#define DIMK 128
#define NT   64
#define NBLK (NT * (NT + 1) / 2)   // 2080

typedef __attribute__((ext_vector_type(8))) short short8;
typedef __attribute__((ext_vector_type(4))) float f32x4;
typedef __attribute__((address_space(3))) uint32_t lds_u32;
typedef const __attribute__((address_space(1))) uint32_t glb_u32;

__device__ __forceinline__ unsigned short bf16_rne(float f) {
  uint32_t u = __float_as_uint(f);
  u += 0x7FFFu + ((u >> 16) & 1u);
  return (unsigned short)(u >> 16);
}

// ws: xhi bf16[NR*DIMK] (2MB) | xlo (2MB) | gP f32[NR] | gN f32[NR] | counter

__global__ __launch_bounds__(256) void normalize_split_kernel(
    const float* __restrict__ x, unsigned short* __restrict__ xhi,
    unsigned short* __restrict__ xlo, float* __restrict__ gP,
    float* __restrict__ gN, int* __restrict__ counter) {
  if (blockIdx.x < 32)      gP[blockIdx.x * 256 + threadIdx.x] = 0.f;
  else if (blockIdx.x < 64) gN[(blockIdx.x - 32) * 256 + threadIdx.x] = 0.f;
  if (blockIdx.x == 64 && threadIdx.x == 0) *counter = 0;

  const int wave = threadIdx.x >> 6;
  const int lane = threadIdx.x & 63;
  const int row  = blockIdx.x * 4 + wave;
  const float2 v = ((const float2*)(x + (size_t)row * DIMK))[lane];
  float ss = v.x * v.x + v.y * v.y;
  #pragma unroll
  for (int s = 1; s < 64; s <<= 1) ss += __shfl_xor(ss, s);
  const float r = rsqrtf(ss);
  const float a = v.x * r, b = v.y * r;
  const unsigned short ha = bf16_rne(a), hb = bf16_rne(b);
  const float haf = __uint_as_float((uint32_t)ha << 16);
  const float hbf = __uint_as_float((uint32_t)hb << 16);
  ushort2 hi, lo;
  hi.x = ha; hi.y = hb;
  lo.x = bf16_rne(a - haf); lo.y = bf16_rne(b - hbf);
  ((ushort2*)xhi)[(size_t)row * 64 + lane] = hi;
  ((ushort2*)xlo)[(size_t)row * 64 + lane] = lo;
}

__global__ __launch_bounds__(256) void simloss_kernel(
    const unsigned short* __restrict__ xhi, const unsigned short* __restrict__ xlo,
    const int* __restrict__ tgt, float* __restrict__ gP, float* __restrict__ gN,
    int* __restrict__ counter, float* __restrict__ out) {
  __shared__ unsigned short AsH[128 * 64], AsL[128 * 64], BsH[128 * 64];  // 48KB
  __shared__ int tAs[128], tBs[128];
  __shared__ float red[256];
  __shared__ int islast;

  // triangular decode: idx -> (bi, bj), bi <= bj
  const int idx = blockIdx.x;
  int bi = (int)floorf((129.0f - sqrtf(129.0f * 129.0f - 8.0f * (float)idx)) * 0.5f);
  if (bi < 0) bi = 0;
  if (bi > NT - 1) bi = NT - 1;
  while (NT * bi - bi * (bi - 1) / 2 > idx) --bi;
  while (NT * (bi + 1) - (bi + 1) * bi / 2 <= idx) ++bi;
  const int bj = bi + idx - (NT * bi - bi * (bi - 1) / 2);
  const int i0 = bi * 128, j0 = bj * 128;
  const bool offdiag = (bi != bj);

  const int tid  = threadIdx.x;
  const int wave = tid >> 6, lane = tid & 63;
  const int wy = wave >> 1, wx = wave & 1;
  const int q = lane >> 4, mcol = lane & 15;

  if (tid < 128) tAs[tid] = tgt[i0 + tid];
  else           tBs[tid - 128] = tgt[j0 + tid - 128];

  // staging: 3 tiles x 16 segs (8 rows x 128B) = 48 segs, 12 per wave
  const unsigned short* ghA = xhi + (size_t)i0 * DIMK;
  const unsigned short* glA = xlo + (size_t)i0 * DIMK;
  const unsigned short* ghB = xhi + (size_t)j0 * DIMK;
  const int srow = lane >> 3;                 // row within seg (0..7)
  const int gc   = (lane & 7) ^ srow;         // swizzled global chunk for LDS slot lane&7

  f32x4 acc[4][4];
  #pragma unroll
  for (int r = 0; r < 4; ++r)
    #pragma unroll
    for (int c = 0; c < 4; ++c)
      acc[r][c] = (f32x4){0.f, 0.f, 0.f, 0.f};

  for (int kc = 0; kc < 2; ++kc) {
    __syncthreads();  // previous readers done before overwrite (covers tAs/tBs on kc==0)
    #pragma unroll
    for (int t = 0; t < 12; ++t) {
      const int segid = wave * 12 + t;
      const int tile = segid >> 4, seg = segid & 15;
      const unsigned short* g = (tile == 0) ? ghA : (tile == 1) ? glA : ghB;
      unsigned short* l = (tile == 0) ? AsH : (tile == 1) ? AsL : BsH;
      const unsigned short* gp = g + (size_t)(seg * 8 + srow) * DIMK + kc * 64 + gc * 8;
      __builtin_amdgcn_global_load_lds((glb_u32*)gp, (lds_u32*)&l[seg * 512], 16, 0, 0);
    }
    __syncthreads();

    #pragma unroll
    for (int s = 0; s < 2; ++s) {
      const int ko = ((s * 4 + q) ^ (mcol & 7)) * 8;  // swizzled 16B chunk in 128B row
      short8 ah[4], al[4], bh[4];
      #pragma unroll
      for (int r = 0; r < 4; ++r)
        ah[r] = *(const short8*)&AsH[(wy * 64 + r * 16 + mcol) * 64 + ko];
      #pragma unroll
      for (int c = 0; c < 4; ++c)
        bh[c] = *(const short8*)&BsH[(wx * 64 + c * 16 + mcol) * 64 + ko];
      #pragma unroll
      for (int r = 0; r < 4; ++r)
        #pragma unroll
        for (int c = 0; c < 4; ++c)
          acc[r][c] = __builtin_amdgcn_mfma_f32_16x16x32_bf16(ah[r], bh[c], acc[r][c], 0, 0, 0);
      #pragma unroll
      for (int r = 0; r < 4; ++r)
        al[r] = *(const short8*)&AsL[(wy * 64 + r * 16 + mcol) * 64 + ko];
      #pragma unroll
      for (int r = 0; r < 4; ++r)
        #pragma unroll
        for (int c = 0; c < 4; ++c)
          acc[r][c] = __builtin_amdgcn_mfma_f32_16x16x32_bf16(al[r], bh[c], acc[r][c], 0, 0, 0);
    }
  }

  // fused epilogue. C layout: col = lane&15, row = q*4 + reg
  int tb[4];
  #pragma unroll
  for (int c = 0; c < 4; ++c) tb[c] = tBs[wx * 64 + c * 16 + mcol];

  float colp[4] = {0.f, 0.f, 0.f, 0.f};
  float coln[4] = {0.f, 0.f, 0.f, 0.f};

  #pragma unroll
  for (int r = 0; r < 4; ++r) {
    #pragma unroll
    for (int reg = 0; reg < 4; ++reg) {
      const int ta = tAs[wy * 64 + r * 16 + q * 4 + reg];
      float vsp = 0.f, vsn = 0.f;
      #pragma unroll
      for (int c = 0; c < 4; ++c) {
        const float s  = acc[r][c][reg];
        const bool pos = (ta == tb[c]);
        const float ap = fmaxf(1.25f - s, 0.f);
        const float an = fmaxf(s - 0.25f, 0.f);
        const float arg = pos ? ap * fmaf(s, 64.f, -48.f) : an * an * 64.f;
        const float e = __expf(arg);
        const float ep = pos ? e : 0.f;
        const float en = pos ? 0.f : e;
        vsp += ep; vsn += en;
        colp[c] += ep; coln[c] += en;
      }
      #pragma unroll
      for (int s2 = 1; s2 < 16; s2 <<= 1) {
        vsp += __shfl_xor(vsp, s2);
        vsn += __shfl_xor(vsn, s2);
      }
      if (mcol == 0) {
        const int row = i0 + wy * 64 + r * 16 + q * 4 + reg;
        atomicAdd(&gP[row], vsp);
        atomicAdd(&gN[row], vsn);
      }
    }
  }
  if (offdiag) {  // transpose contributions -> rows j
    #pragma unroll
    for (int c = 0; c < 4; ++c) {
      colp[c] += __shfl_xor(colp[c], 16); colp[c] += __shfl_xor(colp[c], 32);
      coln[c] += __shfl_xor(coln[c], 16); coln[c] += __shfl_xor(coln[c], 32);
    }
    if (q == 0) {
      #pragma unroll
      for (int c = 0; c < 4; ++c) {
        const int col = j0 + wx * 64 + c * 16 + mcol;
        atomicAdd(&gP[col], colp[c]);
        atomicAdd(&gN[col], coln[c]);
      }
    }
  }

  // ---- fence-free last-block finalize ----
  __builtin_amdgcn_s_waitcnt(0);   // my atomics ack'd before counter bump
  __syncthreads();
  if (tid == 0) islast = (atomicAdd(counter, 1) == NBLK - 1) ? 1 : 0;
  __syncthreads();
  if (islast) {
    float local = 0.f;
    #pragma unroll 1
    for (int b = 0; b < 4; ++b) {
      const int base = b * 2048 + tid * 8;
      float p[8], n[8];
      #pragma unroll
      for (int u = 0; u < 8; ++u) p[u] = atomicAdd(&gP[base + u], 0.0f);
      #pragma unroll
      for (int u = 0; u < 8; ++u) n[u] = atomicAdd(&gN[base + u], 0.0f);
      #pragma unroll
      for (int u = 0; u < 8; ++u) local += log1pf(p[u] * n[u]);
    }
    red[tid] = local;
    __syncthreads();
    for (int s2 = 128; s2 > 0; s2 >>= 1) {
      if (tid < s2) red[tid] += red[tid + s2];
      __syncthreads();
    }
    if (tid == 0) out[0] = red[0] / (float)NR;
  }
}

extern "C" void kernel_launch(void* const* d_in, const int* in_sizes, int n_in,
                              void* d_out, int out_size, void* d_ws, size_t ws_size,
                              hipStream_t stream) {
  const float* x  = (const float*)d_in[0];
  const int* tgt  = (const int*)d_in[1];
  float* out      = (float*)d_out;

  unsigned short* xhi = (unsigned short*)d_ws;
  unsigned short* xlo = xhi + (size_t)NR * DIMK;
  float* gP = (float*)((char*)d_ws + (size_t)NR * DIMK * 4);
  float* gN = gP + NR;
  int* counter = (int*)(gN + NR);

  normalize_split_kernel<<<NR / 4, 256, 0, stream>>>(x, xhi, xlo, gP, gN, counter);
  simloss_kernel<<<NBLK, 256, 0, stream>>>(xhi, xlo, tgt, gP, gN, counter, out);
}

// Round 6
// 130.805 us; speedup vs baseline: 2.0258x; 1.1578x over previous
//
#include <hip/hip_runtime.h>
#include <math.h>

// CircleLoss fused, chunk-persistent MFMA pipeline (R6).
// sim = xn @ xn^T, 2-term split-bf16: sim ~= (hiA+loA).hiB  (drop A.loB ~2e-4).
// Upper-triangular 128x128 tiles grouped into chunks: block = (panel bi, up to
// 4 consecutive bj). A panel (hi+lo, full K) staged once -> A-frags in REGISTERS
// for the whole chunk; LDS region reused as B double-buffers with
// global_load_lds prefetch one tile ahead (raw s_barrier + waitcnt vm0/lgkm0 --
// loads are ~1 tile old => near-zero stall). Row exp-sums accumulate in
// registers across the chunk (one shuffle-reduce + atomic flush per chunk);
// col sums flushed with one-tile delay so atomic RTT hides behind epilogue.
// loss = mean(log1p(sumP*sumN)); fence-free counter finalize (R4/R5-proven).

#define NR    8192
#define DIMK  128
#define NT    64
#define CHUNK 4
#define NBLKS 544   // sum over panels of ceil((64-bi)/4)

typedef __attribute__((ext_vector_type(8))) short short8;
typedef __attribute__((ext_vector_type(4))) float f32x4;
typedef __attribute__((address_space(3))) uint32_t lds_u32;
typedef const __attribute__((address_space(1))) uint32_t glb_u32;

__device__ __forceinline__ unsigned short bf16_rne(float f) {
  uint32_t u = __float_as_uint(f);
  u += 0x7FFFu + ((u >> 16) & 1u);
  return (unsigned short)(u >> 16);
}

// ws: xhi bf16[NR*DIMK] (2MB) | xlo (2MB) | gP f32[NR] | gN f32[NR] | counter

__global__ __launch_bounds__(256) void normalize_split_kernel(
    const float* __restrict__ x, unsigned short* __restrict__ xhi,
    unsigned short* __restrict__ xlo, float* __restrict__ gP,
    float* __restrict__ gN, int* __restrict__ counter) {
  if (blockIdx.x < 32)      gP[blockIdx.x * 256 + threadIdx.x] = 0.f;
  else if (blockIdx.x < 64) gN[(blockIdx.x - 32) * 256 + threadIdx.x] = 0.f;
  if (blockIdx.x == 64 && threadIdx.x == 0) *counter = 0;

  const int wave = threadIdx.x >> 6;
  const int lane = threadIdx.x & 63;
  const int row  = blockIdx.x * 4 + wave;
  const float2 v = ((const float2*)(x + (size_t)row * DIMK))[lane];
  float ss = v.x * v.x + v.y * v.y;
  #pragma unroll
  for (int s = 1; s < 64; s <<= 1) ss += __shfl_xor(ss, s);
  const float r = rsqrtf(ss);
  const float a = v.x * r, b = v.y * r;
  const unsigned short ha = bf16_rne(a), hb = bf16_rne(b);
  const float haf = __uint_as_float((uint32_t)ha << 16);
  const float hbf = __uint_as_float((uint32_t)hb << 16);
  ushort2 hi, lo;
  hi.x = ha; hi.y = hb;
  lo.x = bf16_rne(a - haf); lo.y = bf16_rne(b - hbf);
  ((ushort2*)xhi)[(size_t)row * 64 + lane] = hi;
  ((ushort2*)xlo)[(size_t)row * 64 + lane] = lo;
}

__global__ __launch_bounds__(512, 2) void simloss_kernel(
    const unsigned short* __restrict__ xhi, const unsigned short* __restrict__ xlo,
    const int* __restrict__ tgt, float* __restrict__ gP, float* __restrict__ gN,
    int* __restrict__ counter, float* __restrict__ out) {
  __shared__ unsigned short S[32768];   // 64KB: A(hi|lo) stage, then B0|B1
  __shared__ int tAs[128];
  __shared__ int tBs[2][128];
  __shared__ float red[512];
  __shared__ int islast;

  const int tid  = threadIdx.x;
  const int wave = tid >> 6, lane = tid & 63;
  const int wy = wave & 3, wx = wave >> 2;       // wave grid 4x2: 32 rows x 64 cols
  const int q = lane >> 4, mcol = lane & 15;

  // ---- decode blockIdx.x -> (bi, bj0, ntile) ----
  int w = blockIdx.x, bi = 0, sz = NT;
  while (w >= (sz + CHUNK - 1) / CHUNK) { w -= (sz + CHUNK - 1) / CHUNK; ++bi; --sz; }
  const int bj0 = bi + w * CHUNK;
  const int ntile = min(CHUNK, NT - bj0);
  const int i0 = bi * 128;

  // ---- prologue: stage A panel (hi+lo, full K = 256B rows, 16 chunks/row) ----
  // LDS swizzle: phys 16B-chunk = logical chunk ^ (row & 15). Staging permutes
  // the GLOBAL source per lane (global_load_lds dest is lane-pinned).
  {
    const unsigned short* ghA = xhi + (size_t)i0 * DIMK;
    const unsigned short* glA = xlo + (size_t)i0 * DIMK;
    #pragma unroll
    for (int g = 0; g < 4; ++g) {
      const int r  = wave * 16 + g * 4 + (lane >> 4);
      const int sc = (lane & 15) ^ (r & 15);
      __builtin_amdgcn_global_load_lds((glb_u32*)(ghA + (size_t)r * DIMK + sc * 8),
          (lds_u32*)&S[(wave * 16 + g * 4) * 128], 16, 0, 0);
      __builtin_amdgcn_global_load_lds((glb_u32*)(glA + (size_t)r * DIMK + sc * 8),
          (lds_u32*)&S[16384 + (wave * 16 + g * 4) * 128], 16, 0, 0);
    }
  }
  if (tid < 128) tAs[tid] = tgt[i0 + tid];
  __syncthreads();   // full drain: A staged

  // A fragments -> registers for the whole chunk (row % 16 == mcol)
  short8 Ah[2][4], Al[2][4];
  #pragma unroll
  for (int fr = 0; fr < 2; ++fr) {
    const int r = wy * 32 + fr * 16 + mcol;
    #pragma unroll
    for (int ks = 0; ks < 4; ++ks) {
      const int pc = (ks * 4 + q) ^ mcol;
      Ah[fr][ks] = *(const short8*)&S[r * 128 + pc * 8];
      Al[fr][ks] = *(const short8*)&S[16384 + r * 128 + pc * 8];
    }
  }
  int ta[2][4];
  #pragma unroll
  for (int fr = 0; fr < 2; ++fr)
    #pragma unroll
    for (int rg = 0; rg < 4; ++rg)
      ta[fr][rg] = tAs[wy * 32 + fr * 16 + q * 4 + rg];
  __builtin_amdgcn_s_waitcnt(0);
  __syncthreads();   // all waves' A reads drained -> S reusable as B buffers

  // ---- issue B0 + targets ----
  if (tid < 128) tBs[0][tid] = tgt[bj0 * 128 + tid];
  {
    const unsigned short* gb = xhi + (size_t)bj0 * 128 * DIMK;
    #pragma unroll
    for (int g = 0; g < 4; ++g) {
      const int r  = wave * 16 + g * 4 + (lane >> 4);
      const int sc = (lane & 15) ^ (r & 15);
      __builtin_amdgcn_global_load_lds((glb_u32*)(gb + (size_t)r * DIMK + sc * 8),
          (lds_u32*)&S[(wave * 16 + g * 4) * 128], 16, 0, 0);
    }
  }

  float rowP[2][4] = {{0.f}}, rowN[2][4] = {{0.f}};
  float pP[4], pN[4];
  int pcol = -1;   // pending (delayed) column-flush base, uniform

  for (int t = 0; t < ntile; ++t) {
    const int bj = bj0 + t;
    // B(t) loads were issued one full tile ago; vm0 also covers old atomics.
    // lgkm0 covers the tBs ds_writes. exp ignored. simm16 = vm0|exp7|lgkm0 = 112.
    __builtin_amdgcn_s_waitcnt(112);
    __builtin_amdgcn_s_barrier();

    // prefetch B(t+1) + its targets
    if (t + 1 < ntile) {
      if (tid < 128) tBs[(t + 1) & 1][tid] = tgt[(bj + 1) * 128 + tid];
      const unsigned short* gb = xhi + (size_t)(bj + 1) * 128 * DIMK;
      unsigned short* dst = &S[((t + 1) & 1) * 16384];
      #pragma unroll
      for (int g = 0; g < 4; ++g) {
        const int r  = wave * 16 + g * 4 + (lane >> 4);
        const int sc = (lane & 15) ^ (r & 15);
        __builtin_amdgcn_global_load_lds((glb_u32*)(gb + (size_t)r * DIMK + sc * 8),
            (lds_u32*)&dst[(wave * 16 + g * 4) * 128], 16, 0, 0);
      }
    }

    // ---- compute tile t ----
    const unsigned short* Bb = &S[(t & 1) * 16384];
    f32x4 acc[2][4];
    #pragma unroll
    for (int fr = 0; fr < 2; ++fr)
      #pragma unroll
      for (int fc = 0; fc < 4; ++fc)
        acc[fr][fc] = (f32x4){0.f, 0.f, 0.f, 0.f};
    #pragma unroll
    for (int ks = 0; ks < 4; ++ks) {
      short8 bh[4];
      #pragma unroll
      for (int fc = 0; fc < 4; ++fc) {
        const int rb = wx * 64 + fc * 16 + mcol;
        const int pc = (ks * 4 + q) ^ mcol;
        bh[fc] = *(const short8*)&Bb[rb * 128 + pc * 8];
      }
      #pragma unroll
      for (int fc = 0; fc < 4; ++fc) {
        acc[0][fc] = __builtin_amdgcn_mfma_f32_16x16x32_bf16(Ah[0][ks], bh[fc], acc[0][fc], 0, 0, 0);
        acc[1][fc] = __builtin_amdgcn_mfma_f32_16x16x32_bf16(Ah[1][ks], bh[fc], acc[1][fc], 0, 0, 0);
        acc[0][fc] = __builtin_amdgcn_mfma_f32_16x16x32_bf16(Al[0][ks], bh[fc], acc[0][fc], 0, 0, 0);
        acc[1][fc] = __builtin_amdgcn_mfma_f32_16x16x32_bf16(Al[1][ks], bh[fc], acc[1][fc], 0, 0, 0);
      }
    }

    // flush previous tile's column sums here: atomic RTT hides behind epilogue
    if (pcol >= 0) {
      #pragma unroll
      for (int fc = 0; fc < 4; ++fc) {
        float a = pP[fc], b = pN[fc];
        a += __shfl_xor(a, 16); a += __shfl_xor(a, 32);
        b += __shfl_xor(b, 16); b += __shfl_xor(b, 32);
        if (q == 0) {
          atomicAdd(&gP[pcol + fc * 16 + mcol], a);
          atomicAdd(&gN[pcol + fc * 16 + mcol], b);
        }
      }
    }

    // ---- epilogue: C layout col = mcol, row = q*4 + reg ----
    int tb[4];
    #pragma unroll
    for (int fc = 0; fc < 4; ++fc) tb[fc] = tBs[t & 1][wx * 64 + fc * 16 + mcol];
    float cP[4] = {0.f, 0.f, 0.f, 0.f}, cN[4] = {0.f, 0.f, 0.f, 0.f};
    #pragma unroll
    for (int fr = 0; fr < 2; ++fr) {
      #pragma unroll
      for (int rg = 0; rg < 4; ++rg) {
        const int taa = ta[fr][rg];
        float vp = 0.f, vn = 0.f;
        #pragma unroll
        for (int fc = 0; fc < 4; ++fc) {
          const float s  = acc[fr][fc][rg];
          const bool pos = (taa == tb[fc]);
          const float ap = fmaxf(1.25f - s, 0.f);
          const float an = fmaxf(s - 0.25f, 0.f);
          const float arg = pos ? ap * fmaf(s, 64.f, -48.f) : an * an * 64.f;
          const float e = __expf(arg);
          const float ep = pos ? e : 0.f;
          const float en = pos ? 0.f : e;
          vp += ep; vn += en;
          cP[fc] += ep; cN[fc] += en;
        }
        rowP[fr][rg] += vp;   // register row accumulation across the chunk
        rowN[fr][rg] += vn;
      }
    }
    if (bj != bi) {   // defer col flush one tile (diag tile: counted once, no transpose)
      #pragma unroll
      for (int fc = 0; fc < 4; ++fc) { pP[fc] = cP[fc]; pN[fc] = cN[fc]; }
      pcol = bj * 128 + wx * 64;
    } else {
      pcol = -1;
    }
  }

  // last pending column flush
  if (pcol >= 0) {
    #pragma unroll
    for (int fc = 0; fc < 4; ++fc) {
      float a = pP[fc], b = pN[fc];
      a += __shfl_xor(a, 16); a += __shfl_xor(a, 32);
      b += __shfl_xor(b, 16); b += __shfl_xor(b, 32);
      if (q == 0) {
        atomicAdd(&gP[pcol + fc * 16 + mcol], a);
        atomicAdd(&gN[pcol + fc * 16 + mcol], b);
      }
    }
  }

  // row flush: one shuffle-reduce + atomic set per CHUNK (was per tile)
  #pragma unroll
  for (int fr = 0; fr < 2; ++fr) {
    #pragma unroll
    for (int rg = 0; rg < 4; ++rg) {
      float vp = rowP[fr][rg], vn = rowN[fr][rg];
      #pragma unroll
      for (int m = 1; m < 16; m <<= 1) {
        vp += __shfl_xor(vp, m);
        vn += __shfl_xor(vn, m);
      }
      if (mcol == 0) {
        const int row = i0 + wy * 32 + fr * 16 + q * 4 + rg;
        atomicAdd(&gP[row], vp);
        atomicAdd(&gN[row], vn);
      }
    }
  }

  // ---- fence-free last-block finalize ----
  __builtin_amdgcn_s_waitcnt(0);   // my atomics ack'd before counter bump
  __syncthreads();
  if (tid == 0) islast = (atomicAdd(counter, 1) == NBLKS - 1) ? 1 : 0;
  __syncthreads();
  if (islast) {
    float local = 0.f;
    #pragma unroll 1
    for (int b = 0; b < 2; ++b) {
      const int base = b * 4096 + tid * 8;
      float p[8], n[8];
      #pragma unroll
      for (int u = 0; u < 8; ++u) p[u] = atomicAdd(&gP[base + u], 0.0f);
      #pragma unroll
      for (int u = 0; u < 8; ++u) n[u] = atomicAdd(&gN[base + u], 0.0f);
      #pragma unroll
      for (int u = 0; u < 8; ++u) local += log1pf(p[u] * n[u]);
    }
    red[tid] = local;
    __syncthreads();
    for (int s2 = 256; s2 > 0; s2 >>= 1) {
      if (tid < s2) red[tid] += red[tid + s2];
      __syncthreads();
    }
    if (tid == 0) out[0] = red[0] / (float)NR;
  }
}

extern "C" void kernel_launch(void* const* d_in, const int* in_sizes, int n_in,
                              void* d_out, int out_size, void* d_ws, size_t ws_size,
                              hipStream_t stream) {
  const float* x  = (const float*)d_in[0];
  const int* tgt  = (const int*)d_in[1];
  float* out      = (float*)d_out;

  unsigned short* xhi = (unsigned short*)d_ws;
  unsigned short* xlo = xhi + (size_t)NR * DIMK;
  float* gP = (float*)((char*)d_ws + (size_t)NR * DIMK * 4);
  float* gN = gP + NR;
  int* counter = (int*)(gN + NR);

  normalize_split_kernel<<<NR / 4, 256, 0, stream>>>(x, xhi, xlo, gP, gN, counter);
  simloss_kernel<<<NBLKS, 512, 0, stream>>>(xhi, xlo, tgt, gP, gN, counter, out);
}